// Round 5
// baseline (622.487 us; speedup 1.0000x reference)
//
#include <hip/hip_runtime.h>
#include <hip/hip_bf16.h>
#include <stdint.h>

typedef _Float16 f16;
typedef _Float16 f16x8 __attribute__((ext_vector_type(8)));
typedef _Float16 f16x4 __attribute__((ext_vector_type(4)));
typedef float f32x4 __attribute__((ext_vector_type(4)));
typedef float f32x16 __attribute__((ext_vector_type(16)));

#define T_TOK 8192
#define H_DIM 1024
#define NHEAD 8
#define V_DIM 2048

__device__ __forceinline__ float fast_tanh(float x) {
  float xc = fminf(fmaxf(x, -12.f), 12.f);
  float e = __expf(2.f * xc);
  return (e - 1.f) / (e + 1.f);
}

// ---------- 256x256x64 pipelined 4-phase GEMM, 32x32x16 MFMA, reg-staged ----
// LDS layout per 16KB half-tile (128 rows x 64 k): k-major 16B chunks with XOR:
//   byte(c, r) = c*2048 + (r ^ c)*16      (c = k-chunk 0..7, r = row 0..127)
// -> frag reads are contiguous 16B-per-lane octets (conflict-free);
//    ds_write octets (c=0..7, r fixed) hit distinct quads via r^c.
// Staging: per-thread 8x global_load_dwordx4 (coalesced) -> ds_write_b128.
// Compiler inserts counted vmcnt for load->ds_write deps (T4). setprio (T5).
template <int TANH>
__global__ __launch_bounds__(512, 2) void k_gemm(const f16* __restrict__ A,
                                                 const f16* __restrict__ Bt,
                                                 const float* __restrict__ bias,
                                                 f16* __restrict__ C,
                                                 int M, int N, int K) {
  __shared__ __align__(16) f16 sA[2][16384];
  __shared__ __align__(16) f16 sB[2][16384];
  const int tid = threadIdx.x;
  const int lane = tid & 63;
  const int wid = tid >> 6;
  const int wr = wid >> 2, wc = wid & 3;
  // XCD-aware block swizzle (T1); grids are multiples of 8 blocks
  const int gx = gridDim.x;
  const int id = blockIdx.y * gx + blockIdx.x;
  const int cpx = (gx * gridDim.y) >> 3;
  const int sw = (id & 7) * cpx + (id >> 3);
  const int m0 = (sw / gx) * 256, n0 = (sw % gx) * 256;
  const int NT = K >> 6;
  const int rr31 = lane & 31;  // fragment row (HW-mandated for 32x32 MFMA)
  const int hi = lane >> 5;    // k-half selector

  // staging coords: thread covers rows sr+{0,64,128,192}, k-chunk sc
  const int sr = tid >> 3;  // 0..63
  const int sc = tid & 7;   // 0..7
  const f16* pA = A + (size_t)(m0 + sr) * K + sc * 8;
  const f16* pB = Bt + (size_t)(n0 + sr) * K + sc * 8;
  const size_t rowK = (size_t)64 * K;
  char* sAb = (char*)&sA[0][0];
  char* sBb = (char*)&sB[0][0];
  // ds_write base (within a 32KB tile buffer): half0 row sr, chunk sc
  const int wof = sc * 2048 + ((sr ^ sc) << 4);

  f32x16 acc[4][2] = {};
  f16x8 af0[4], af1[4], bfP[2], bfN[2];
  f16x8 a0, a1, a2, a3, b0, b1, b2, b3;

#define STAGE_ISSUE(kt)                                                        \
  {                                                                            \
    a0 = *(const f16x8*)(pA + (kt));                                           \
    a1 = *(const f16x8*)(pA + rowK + (kt));                                    \
    a2 = *(const f16x8*)(pA + 2 * rowK + (kt));                                \
    a3 = *(const f16x8*)(pA + 3 * rowK + (kt));                                \
    b0 = *(const f16x8*)(pB + (kt));                                           \
    b1 = *(const f16x8*)(pB + rowK + (kt));                                    \
    b2 = *(const f16x8*)(pB + 2 * rowK + (kt));                                \
    b3 = *(const f16x8*)(pB + 3 * rowK + (kt));                                \
  }
#define STAGE_WRITE_A(bb)                                                      \
  {                                                                            \
    char* d = sAb + (bb)*32768 + wof;                                          \
    *(f16x8*)(d) = a0;                                                         \
    *(f16x8*)(d + 1024) = a1;                                                  \
    *(f16x8*)(d + 16384) = a2;                                                 \
    *(f16x8*)(d + 16384 + 1024) = a3;                                          \
  }
#define STAGE_WRITE_B(bb)                                                      \
  {                                                                            \
    char* d = sBb + (bb)*32768 + wof;                                          \
    *(f16x8*)(d) = b0;                                                         \
    *(f16x8*)(d + 1024) = b1;                                                  \
    *(f16x8*)(d + 16384) = b2;                                                 \
    *(f16x8*)(d + 16384 + 1024) = b3;                                          \
  }
  // A frag (k-step q): rows 32*mi + rr31, chunk cq=2q+hi
#define LDA4(dst, base, q)                                                     \
  {                                                                            \
    const int cq = 2 * (q) + hi;                                               \
    const char* p = (base) + wr * 16384 + cq * 2048 + ((rr31 ^ cq) << 4);      \
    dst[0] = *(const f16x8*)(p);                                               \
    dst[1] = *(const f16x8*)(p + 512);                                         \
    dst[2] = *(const f16x8*)(p + 1024);                                        \
    dst[3] = *(const f16x8*)(p + 1536);                                        \
  }
#define LDB2(dst, base, q)                                                     \
  {                                                                            \
    const int cq = 2 * (q) + hi;                                               \
    const char* p = (base) + (wc >> 1) * 16384 + cq * 2048 + ((wc & 1) << 10) +\
                    ((rr31 ^ cq) << 4);                                        \
    dst[0] = *(const f16x8*)(p);                                               \
    dst[1] = *(const f16x8*)(p + 512);                                         \
  }
#define MFMA8(AF, BF)                                                          \
  {                                                                            \
    __builtin_amdgcn_s_setprio(1);                                             \
    _Pragma("unroll") for (int mi = 0; mi < 4; ++mi) {                         \
      _Pragma("unroll") for (int n = 0; n < 2; ++n) {                          \
        acc[mi][n] = __builtin_amdgcn_mfma_f32_32x32x16_f16(                   \
            AF[mi], BF[n], acc[mi][n], 0, 0, 0);                               \
      }                                                                        \
    }                                                                          \
    __builtin_amdgcn_s_setprio(0);                                             \
  }

  // prologue: stage tile 0 into buf 0
  STAGE_ISSUE(0);
  STAGE_WRITE_A(0);
  STAGE_WRITE_B(0);
  asm volatile("s_waitcnt lgkmcnt(0)" ::: "memory");
  __builtin_amdgcn_s_barrier();
  __builtin_amdgcn_sched_barrier(0);
  LDA4(af0, sAb, 0);
  LDB2(bfP, sBb, 0);

#pragma unroll 2
  for (int T = 0; T < NT; ++T) {
    const int buf = T & 1;
    const char* cbA = sAb + buf * 32768;
    const char* cbB = sBb + buf * 32768;
    const int nb = buf ^ 1;
    const bool pre = (T + 1 < NT);
    // ph0: issue next-tile loads; frags q1; MFMA q0
    if (pre) STAGE_ISSUE((size_t)(T + 1) << 6);
    LDA4(af1, cbA, 1);
    LDB2(bfN, cbB, 1);
    __builtin_amdgcn_sched_barrier(0);
    MFMA8(af0, bfP);
    __builtin_amdgcn_s_barrier();
    // ph1: frags q2; MFMA q1
    LDA4(af0, cbA, 2);
    LDB2(bfP, cbB, 2);
    __builtin_amdgcn_sched_barrier(0);
    MFMA8(af1, bfN);
    __builtin_amdgcn_s_barrier();
    // ph2: write A (compiler emits counted vmcnt(4)); frags q3; MFMA q2
    if (pre) STAGE_WRITE_A(nb);
    LDA4(af1, cbA, 3);
    LDB2(bfN, cbB, 3);
    __builtin_amdgcn_sched_barrier(0);
    MFMA8(af0, bfP);
    __builtin_amdgcn_s_barrier();
    // ph3: write B (vmcnt(0) auto); seal writes; preload next q0; MFMA q3
    if (pre) STAGE_WRITE_B(nb);
    asm volatile("s_waitcnt lgkmcnt(0)" ::: "memory");
    __builtin_amdgcn_s_barrier();
    __builtin_amdgcn_sched_barrier(0);
    if (pre) {
      LDA4(af0, sAb + nb * 32768, 0);
      LDB2(bfP, sBb + nb * 32768, 0);
    }
    __builtin_amdgcn_sched_barrier(0);
    MFMA8(af1, bfN);
  }
#undef STAGE_ISSUE
#undef STAGE_WRITE_A
#undef STAGE_WRITE_B
#undef LDA4
#undef LDB2
#undef MFMA8

  // epilogue: 32x32 D layout: col = lane&31, row = (reg&3) + 8*(reg>>2) + 4*hi
  const int ccol0 = n0 + wc * 64 + rr31;
  float bv[2];
#pragma unroll
  for (int n = 0; n < 2; ++n) bv[n] = bias[ccol0 + n * 32];
#pragma unroll
  for (int mi = 0; mi < 4; ++mi) {
#pragma unroll
    for (int rq = 0; rq < 4; ++rq) {
#pragma unroll
      for (int r2 = 0; r2 < 4; ++r2) {
        const int row = m0 + wr * 128 + mi * 32 + r2 + 8 * rq + 4 * hi;
        f16* Crow = C + (size_t)row * N;
#pragma unroll
        for (int n = 0; n < 2; ++n) {
          float v = acc[mi][n][rq * 4 + r2] + bv[n];
          if (TANH) v = fast_tanh(v);
          Crow[ccol0 + n * 32] = (f16)v;
        }
      }
    }
  }
}

// ---------- fp32 -> fp16 elementwise convert ----------
__global__ __launch_bounds__(256) void k_convert(const float* __restrict__ in,
                                                 f16* __restrict__ out, int n4) {
  int i = blockIdx.x * blockDim.x + threadIdx.x;
  if (i >= n4) return;
  const float4 v = ((const float4*)in)[i];
  f16x4 o;
  o[0] = (f16)v.x; o[1] = (f16)v.y; o[2] = (f16)v.z; o[3] = (f16)v.w;
  ((f16x4*)out)[i] = o;
}

// ---------- fp32 [R][C] -> fp16 [C][R] transpose-convert ----------
__global__ void k_transpose(const float* __restrict__ in, f16* __restrict__ out,
                            int R, int C) {
  __shared__ f16 tile[32][33];
  int c0 = blockIdx.x * 32, r0 = blockIdx.y * 32;
  for (int j = threadIdx.y; j < 32; j += 8)
    tile[j][threadIdx.x] = (f16)in[(size_t)(r0 + j) * C + (c0 + threadIdx.x)];
  __syncthreads();
  for (int j = threadIdx.y; j < 32; j += 8)
    out[(size_t)(c0 + j) * R + (r0 + threadIdx.x)] = tile[threadIdx.x][j];
}

// ---------- prior: sigmoid(hidden @ prior_w + b), renormalized over heads ----------
__global__ __launch_bounds__(256) void k_prior(const float* __restrict__ hidden,
                                               const float* __restrict__ pw,
                                               const float* __restrict__ pb,
                                               float* __restrict__ prior) {
  const int wid = threadIdx.x >> 6, lane = threadIdx.x & 63;
  const int t = blockIdx.x * 4 + wid;
  float acc[NHEAD] = {0.f, 0.f, 0.f, 0.f, 0.f, 0.f, 0.f, 0.f};
  const float* hrow = hidden + (size_t)t * H_DIM;
  for (int k = lane; k < H_DIM; k += 64) {
    float x = hrow[k];
    const float* wr = pw + k * NHEAD;
#pragma unroll
    for (int h = 0; h < NHEAD; ++h) acc[h] += x * wr[h];
  }
#pragma unroll
  for (int h = 0; h < NHEAD; ++h) {
#pragma unroll
    for (int off = 32; off >= 1; off >>= 1) acc[h] += __shfl_xor(acc[h], off);
  }
  if (lane == 0) {
    float p[NHEAD], s = 0.f;
#pragma unroll
    for (int h = 0; h < NHEAD; ++h) {
      p[h] = 1.f / (1.f + __expf(-(acc[h] + pb[h])));
      s += p[h];
    }
    float inv = 1.f / (s + 1e-8f);
#pragma unroll
    for (int h = 0; h < NHEAD; ++h) prior[t * NHEAD + h] = p[h] * inv;
  }
}

// ---------- per-token softmax over V per head + prior-weighted combine ----------
__global__ __launch_bounds__(256) void k_softmax(const f16* __restrict__ logits,
                                                 const float* __restrict__ prior,
                                                 float* __restrict__ out) {
  __shared__ float red[4];
  const int t = blockIdx.x;
  const int tid = threadIdx.x, lane = tid & 63, wid = tid >> 6;
  float oa[8] = {0.f, 0.f, 0.f, 0.f, 0.f, 0.f, 0.f, 0.f};
  const int v0 = tid * 8;
#pragma unroll 1
  for (int h = 0; h < NHEAD; ++h) {
    f16x8 x = *(const f16x8*)(logits + ((size_t)t * NHEAD + h) * V_DIM + v0);
    float xv[8], mx = -1e30f;
#pragma unroll
    for (int j = 0; j < 8; j++) { xv[j] = (float)x[j]; mx = fmaxf(mx, xv[j]); }
#pragma unroll
    for (int off = 32; off >= 1; off >>= 1) mx = fmaxf(mx, __shfl_xor(mx, off));
    if (lane == 0) red[wid] = mx;
    __syncthreads();
    mx = fmaxf(fmaxf(red[0], red[1]), fmaxf(red[2], red[3]));
    __syncthreads();
    float e[8], s = 0.f;
#pragma unroll
    for (int j = 0; j < 8; j++) { e[j] = __expf(xv[j] - mx); s += e[j]; }
#pragma unroll
    for (int off = 32; off >= 1; off >>= 1) s += __shfl_xor(s, off);
    if (lane == 0) red[wid] = s;
    __syncthreads();
    s = red[0] + red[1] + red[2] + red[3];
    __syncthreads();
    const float coef = prior[t * NHEAD + h] / s;
#pragma unroll
    for (int j = 0; j < 8; j++) oa[j] += coef * e[j];
  }
  float4* op = (float4*)(out + (size_t)t * V_DIM + v0);
  op[0] = make_float4(oa[0], oa[1], oa[2], oa[3]);
  op[1] = make_float4(oa[4], oa[5], oa[6], oa[7]);
}

extern "C" void kernel_launch(void* const* d_in, const int* in_sizes, int n_in,
                              void* d_out, int out_size, void* d_ws, size_t ws_size,
                              hipStream_t stream) {
  const float* hidden   = (const float*)d_in[0];
  const float* prior_w  = (const float*)d_in[1];
  const float* prior_b  = (const float*)d_in[2];
  const float* latent_w = (const float*)d_in[3];
  const float* latent_b = (const float*)d_in[4];
  const float* output_w = (const float*)d_in[5];
  const float* output_b = (const float*)d_in[6];
  float* out = (float*)d_out;

  char* ws = (char*)d_ws;
  size_t off = 0;
  auto alloc = [&](size_t bytes) -> void* {
    void* p = ws + off;
    off += (bytes + 255) & ~(size_t)255;
    return p;
  };
  f16* hidden_h = (f16*)alloc((size_t)T_TOK * H_DIM * 2);          // [8192][1024]
  f16* lw_t     = (f16*)alloc((size_t)NHEAD * H_DIM * H_DIM * 2);  // [8192][1024]
  f16* ow_t     = (f16*)alloc((size_t)V_DIM * H_DIM * 2);          // [2048][1024]
  float* prior  = (float*)alloc((size_t)T_TOK * NHEAD * 4);

  // tc=2048: logits chunk (64MiB) + latent chunk stay L3-resident between
  // GEMM2 and softmax (round-3-proven locality). Shrink if ws is tight.
  int tc = 2048;
  while (tc > 256) {
    size_t need = off + (size_t)tc * NHEAD * H_DIM * 2 + 256 +
                  (size_t)tc * NHEAD * V_DIM * 2 + 256;
    if (need <= ws_size) break;
    tc >>= 1;
  }
  f16* latent_h = (f16*)alloc((size_t)tc * NHEAD * H_DIM * 2);  // [tc*8][1024]
  f16* logits_h = (f16*)alloc((size_t)tc * NHEAD * V_DIM * 2);  // [tc*8][2048]

  // prep passes
  k_convert<<<(T_TOK * H_DIM / 4 + 255) / 256, 256, 0, stream>>>(
      hidden, hidden_h, T_TOK * H_DIM / 4);
  k_transpose<<<dim3(NHEAD * H_DIM / 32, H_DIM / 32), dim3(32, 8), 0, stream>>>(
      latent_w, lw_t, H_DIM, NHEAD * H_DIM);
  k_transpose<<<dim3(V_DIM / 32, H_DIM / 32), dim3(32, 8), 0, stream>>>(
      output_w, ow_t, H_DIM, V_DIM);
  k_prior<<<T_TOK / 4, 256, 0, stream>>>(hidden, prior_w, prior_b, prior);

  const int nchunk = T_TOK / tc;
  for (int c = 0; c < nchunk; ++c) {
    const f16* Ah = hidden_h + (size_t)c * tc * H_DIM;
    // latent = tanh(hidden @ latent_w + latent_b), stored [tc*8][1024] f16
    k_gemm<1><<<dim3(NHEAD * H_DIM / 256, tc / 256), 512, 0, stream>>>(
        Ah, lw_t, latent_b, latent_h, tc, NHEAD * H_DIM, H_DIM);
    // logits = latent @ output_w + output_b, stored [tc*8][2048] f16
    k_gemm<0><<<dim3(V_DIM / 256, tc * NHEAD / 256), 512, 0, stream>>>(
        latent_h, ow_t, output_b, logits_h, tc * NHEAD, V_DIM, H_DIM);
    // softmax over V per head, prior-weighted sum over heads
    k_softmax<<<tc, 256, 0, stream>>>(logits_h, prior + (size_t)c * tc * NHEAD,
                                      out + (size_t)c * tc * V_DIM);
  }
}

// Round 6
// 616.961 us; speedup vs baseline: 1.0090x; 1.0090x over previous
//
#include <hip/hip_runtime.h>
#include <hip/hip_bf16.h>
#include <stdint.h>

typedef _Float16 f16;
typedef _Float16 f16x8 __attribute__((ext_vector_type(8)));
typedef _Float16 f16x4 __attribute__((ext_vector_type(4)));
typedef float f32x4 __attribute__((ext_vector_type(4)));
typedef float f32x16 __attribute__((ext_vector_type(16)));

#define T_TOK 8192
#define H_DIM 1024
#define NHEAD 8
#define V_DIM 2048

// global -> LDS direct load, 16B per lane. LDS dest = wave-uniform base + lane*16.
__device__ __forceinline__ void gload16(const void* g, void* l) {
  __builtin_amdgcn_global_load_lds(
      (const __attribute__((address_space(1))) void*)(uintptr_t)g,
      (__attribute__((address_space(3))) void*)(unsigned)(uintptr_t)l,
      16, 0, 0);
}

__device__ __forceinline__ float fast_tanh(float x) {
  float xc = fminf(fmaxf(x, -12.f), 12.f);
  float e = __expf(2.f * xc);
  return (e - 1.f) / (e + 1.f);
}

// Stage one half-tile (128 rows x 64 f16 = 16KB) with 2 global_load_lds.
// Source col-chunk = (tid&7) ^ (row&7); dest linear -> LDS[row][slot] holds
// global chunk (slot ^ (row&7)); reader applies same XOR.
__device__ __forceinline__ void stage_half(const f16* __restrict__ gRowBase,
                                           char* ldsHalf, int tid, int sl8,
                                           int Kd) {
  const int srow = tid >> 3;
  char* wuni = ldsHalf + ((tid >> 6) << 10);  // wave-uniform base
  gload16(gRowBase + (size_t)srow * Kd + sl8, wuni);
  gload16(gRowBase + (size_t)(srow + 64) * Kd + sl8, wuni + 8192);
}

// ---------- 256x256x64 pipelined 4-phase GEMM, 32x32x16 MFMA ----------
// C = epi(A[M,K]*Bt[N,K]^T + bias). 8 waves (2M x 4N), per-wave 128x64 out =
// acc[4][2] f32x16 (AGPR). af ping-pong one k-step ahead; 1 barrier/phase;
// counted vmcnt(4) once per K-tile (T4); setprio around MFMA cluster (T5).
// [R4-proven: 1.83 PF on GEMM2 at tc=8192 — kept byte-identical this round]
template <int TANH>
__global__ __launch_bounds__(512, 2) void k_gemm(const f16* __restrict__ A,
                                                 const f16* __restrict__ Bt,
                                                 const float* __restrict__ bias,
                                                 f16* __restrict__ C,
                                                 int M, int N, int K) {
  __shared__ __align__(16) f16 sA[2][16384];
  __shared__ __align__(16) f16 sB[2][16384];
  const int tid = threadIdx.x;
  const int lane = tid & 63;
  const int wid = tid >> 6;
  const int wr = wid >> 2, wc = wid & 3;
  // XCD-aware block swizzle (T1); all grids here are multiples of 8 blocks
  const int gx = gridDim.x;
  const int id = blockIdx.y * gx + blockIdx.x;
  const int cpx = (gx * gridDim.y) >> 3;
  const int sw = (id & 7) * cpx + (id >> 3);
  const int m0 = (sw / gx) * 256, n0 = (sw % gx) * 256;
  const int NT = K >> 6;  // NT even (K % 128 == 0)
  const int sl8 = ((tid & 7) ^ ((tid >> 3) & 7)) << 3;  // staging src col (f16)
  const int rr31 = lane & 31;   // A/B fragment row (m or n within 32)
  const int hi = lane >> 5;     // k-half selector
  const int l7 = lane & 7;      // row&7 for XOR slot swizzle

  const f16* Ag = A + (size_t)m0 * K;
  const f16* Bg = Bt + (size_t)n0 * K;
  char* sAb = (char*)&sA[0][0];
  char* sBb = (char*)&sB[0][0];

  // prologue: tile0 A+B -> buf0, tile1 B -> buf1
  stage_half(Ag, sAb, tid, sl8, K);
  stage_half(Ag + (size_t)128 * K, sAb + 16384, tid, sl8, K);
  stage_half(Bg, sBb, tid, sl8, K);
  stage_half(Bg + (size_t)128 * K, sBb + 16384, tid, sl8, K);
  stage_half(Bg + 64, sBb + 32768, tid, sl8, K);
  stage_half(Bg + (size_t)128 * K + 64, sBb + 32768 + 16384, tid, sl8, K);
  asm volatile("s_waitcnt vmcnt(4)" ::: "memory");  // tile0 A+B resident
  __builtin_amdgcn_s_barrier();
  __builtin_amdgcn_sched_barrier(0);

  f32x16 acc[4][2] = {};
  f16x8 af0[4], af1[4], bf[2][4];

  // A frag (32x16): lane holds A[row=rr31][k = hi*8 + j]; k-step q -> slot 2q+hi
#define LDA_SET(dst, base, q)                                                  \
  {                                                                            \
    _Pragma("unroll") for (int mi = 0; mi < 4; ++mi) {                         \
      dst[mi] = *(const f16x8*)((base) + wr * 16384 + mi * 4096 + rr31 * 128 + \
                                (((2 * (q) + hi) ^ l7) << 4));                 \
    }                                                                          \
  }
#define LDB(base)                                                              \
  {                                                                            \
    _Pragma("unroll") for (int n = 0; n < 2; ++n) {                            \
      _Pragma("unroll") for (int ks = 0; ks < 4; ++ks) {                       \
        bf[n][ks] = *(const f16x8*)((base) + wc * 8192 + n * 4096 +            \
                                    rr31 * 128 + (((2 * ks + hi) ^ l7) << 4)); \
      }                                                                        \
    }                                                                          \
  }
#define MFMA8(ks, S)                                                           \
  {                                                                            \
    __builtin_amdgcn_s_setprio(1);                                             \
    _Pragma("unroll") for (int mi = 0; mi < 4; ++mi) {                         \
      _Pragma("unroll") for (int n = 0; n < 2; ++n) {                          \
        acc[mi][n] = __builtin_amdgcn_mfma_f32_32x32x16_f16(                   \
            S[mi], bf[n][ks], acc[mi][n], 0, 0, 0);                            \
      }                                                                        \
    }                                                                          \
    __builtin_amdgcn_s_setprio(0);                                             \
  }

  // preload k-step 0 fragments of tile 0
  LDA_SET(af0, sAb, 0);

#define HALF(tt, bc)                                                           \
  {                                                                            \
    const char* cA = sAb + (bc)*32768;                                         \
    const char* cB = sBb + (bc)*32768;                                         \
    char* nA = sAb + ((bc) ^ 1) * 32768;                                       \
    char* nB = sBb + (bc)*32768;                                               \
    const int ktA = ((tt) + 1) << 6, ktB = ((tt) + 2) << 6;                    \
    const bool doA = (tt) + 1 < NT, doB = (tt) + 2 < NT;                       \
    /* ph0 */                                                                  \
    if (doA) stage_half(Ag + ktA, nA, tid, sl8, K);                            \
    LDB(cB);                                                                   \
    LDA_SET(af1, cA, 1);                                                       \
    __builtin_amdgcn_sched_barrier(0);                                         \
    MFMA8(0, af0);                                                             \
    __builtin_amdgcn_s_barrier();                                              \
    /* ph1 */                                                                  \
    if (doA) stage_half(Ag + (size_t)128 * K + ktA, nA + 16384, tid, sl8, K);  \
    LDA_SET(af0, cA, 2);                                                       \
    __builtin_amdgcn_sched_barrier(0);                                         \
    MFMA8(1, af1);                                                             \
    __builtin_amdgcn_s_barrier();                                              \
    /* ph2 */                                                                  \
    if (doB) stage_half(Bg + ktB, nB, tid, sl8, K);                            \
    LDA_SET(af1, cA, 3);                                                       \
    __builtin_amdgcn_sched_barrier(0);                                         \
    MFMA8(2, af0);                                                             \
    __builtin_amdgcn_s_barrier();                                              \
    /* ph3: counted vmcnt; preload next tile ks0 after barrier */              \
    if (doB) stage_half(Bg + (size_t)128 * K + ktB, nB + 16384, tid, sl8, K);  \
    if (doB) {                                                                 \
      asm volatile("s_waitcnt vmcnt(4)" ::: "memory");                         \
    } else {                                                                   \
      asm volatile("s_waitcnt vmcnt(0)" ::: "memory");                         \
    }                                                                          \
    __builtin_amdgcn_s_barrier();                                              \
    __builtin_amdgcn_sched_barrier(0);                                         \
    if (doA) LDA_SET(af0, sAb + ((bc) ^ 1) * 32768, 0);                        \
    __builtin_amdgcn_sched_barrier(0);                                         \
    MFMA8(3, af1);                                                             \
  }

#pragma unroll 1
  for (int T = 0; T < NT; T += 2) {
    HALF(T, 0);
    HALF(T + 1, 1);
  }
#undef HALF
#undef LDA_SET
#undef LDB
#undef MFMA8

  // epilogue: 32x32 D layout: col = lane&31, row = (reg&3) + 8*(reg>>2) + 4*hi
  const int ccol0 = n0 + wc * 64 + rr31;
  float bv[2];
#pragma unroll
  for (int n = 0; n < 2; ++n) bv[n] = bias[ccol0 + n * 32];
#pragma unroll
  for (int mi = 0; mi < 4; ++mi) {
#pragma unroll
    for (int rq = 0; rq < 4; ++rq) {
#pragma unroll
      for (int r2 = 0; r2 < 4; ++r2) {
        const int row = m0 + wr * 128 + mi * 32 + r2 + 8 * rq + 4 * hi;
        f16* Crow = C + (size_t)row * N;
#pragma unroll
        for (int n = 0; n < 2; ++n) {
          float v = acc[mi][n][rq * 4 + r2] + bv[n];
          if (TANH) v = fast_tanh(v);
          Crow[ccol0 + n * 32] = (f16)v;
        }
      }
    }
  }
}

// ---------- fp32 -> fp16 elementwise convert ----------
__global__ __launch_bounds__(256) void k_convert(const float* __restrict__ in,
                                                 f16* __restrict__ out, int n4) {
  int i = blockIdx.x * blockDim.x + threadIdx.x;
  if (i >= n4) return;
  const float4 v = ((const float4*)in)[i];
  f16x4 o;
  o[0] = (f16)v.x; o[1] = (f16)v.y; o[2] = (f16)v.z; o[3] = (f16)v.w;
  ((f16x4*)out)[i] = o;
}

// ---------- fp32 [R][C] -> fp16 [C][R] transpose-convert ----------
__global__ void k_transpose(const float* __restrict__ in, f16* __restrict__ out,
                            int R, int C) {
  __shared__ f16 tile[32][33];
  int c0 = blockIdx.x * 32, r0 = blockIdx.y * 32;
  for (int j = threadIdx.y; j < 32; j += 8)
    tile[j][threadIdx.x] = (f16)in[(size_t)(r0 + j) * C + (c0 + threadIdx.x)];
  __syncthreads();
  for (int j = threadIdx.y; j < 32; j += 8)
    out[(size_t)(c0 + j) * R + (r0 + threadIdx.x)] = tile[threadIdx.x][j];
}

// ---------- prior: sigmoid(hidden @ prior_w + b), renormalized over heads ----------
__global__ __launch_bounds__(256) void k_prior(const float* __restrict__ hidden,
                                               const float* __restrict__ pw,
                                               const float* __restrict__ pb,
                                               float* __restrict__ prior) {
  const int wid = threadIdx.x >> 6, lane = threadIdx.x & 63;
  const int t = blockIdx.x * 4 + wid;
  float acc[NHEAD] = {0.f, 0.f, 0.f, 0.f, 0.f, 0.f, 0.f, 0.f};
  const float* hrow = hidden + (size_t)t * H_DIM;
  for (int k = lane; k < H_DIM; k += 64) {
    float x = hrow[k];
    const float* wr = pw + k * NHEAD;
#pragma unroll
    for (int h = 0; h < NHEAD; ++h) acc[h] += x * wr[h];
  }
#pragma unroll
  for (int h = 0; h < NHEAD; ++h) {
#pragma unroll
    for (int off = 32; off >= 1; off >>= 1) acc[h] += __shfl_xor(acc[h], off);
  }
  if (lane == 0) {
    float p[NHEAD], s = 0.f;
#pragma unroll
    for (int h = 0; h < NHEAD; ++h) {
      p[h] = 1.f / (1.f + __expf(-(acc[h] + pb[h])));
      s += p[h];
    }
    float inv = 1.f / (s + 1e-8f);
#pragma unroll
    for (int h = 0; h < NHEAD; ++h) prior[t * NHEAD + h] = p[h] * inv;
  }
}

// ---------- per-token softmax over V per head + prior-weighted combine ----------
__global__ __launch_bounds__(256) void k_softmax(const f16* __restrict__ logits,
                                                 const float* __restrict__ prior,
                                                 float* __restrict__ out) {
  __shared__ float red[4];
  const int t = blockIdx.x;
  const int tid = threadIdx.x, lane = tid & 63, wid = tid >> 6;
  float oa[8] = {0.f, 0.f, 0.f, 0.f, 0.f, 0.f, 0.f, 0.f};
  const int v0 = tid * 8;
#pragma unroll 1
  for (int h = 0; h < NHEAD; ++h) {
    f16x8 x = *(const f16x8*)(logits + ((size_t)t * NHEAD + h) * V_DIM + v0);
    float xv[8], mx = -1e30f;
#pragma unroll
    for (int j = 0; j < 8; j++) { xv[j] = (float)x[j]; mx = fmaxf(mx, xv[j]); }
#pragma unroll
    for (int off = 32; off >= 1; off >>= 1) mx = fmaxf(mx, __shfl_xor(mx, off));
    if (lane == 0) red[wid] = mx;
    __syncthreads();
    mx = fmaxf(fmaxf(red[0], red[1]), fmaxf(red[2], red[3]));
    __syncthreads();
    float e[8], s = 0.f;
#pragma unroll
    for (int j = 0; j < 8; j++) { e[j] = __expf(xv[j] - mx); s += e[j]; }
#pragma unroll
    for (int off = 32; off >= 1; off >>= 1) s += __shfl_xor(s, off);
    if (lane == 0) red[wid] = s;
    __syncthreads();
    s = red[0] + red[1] + red[2] + red[3];
    __syncthreads();
    const float coef = prior[t * NHEAD + h] / s;
#pragma unroll
    for (int j = 0; j < 8; j++) oa[j] += coef * e[j];
  }
  float4* op = (float4*)(out + (size_t)t * V_DIM + v0);
  op[0] = make_float4(oa[0], oa[1], oa[2], oa[3]);
  op[1] = make_float4(oa[4], oa[5], oa[6], oa[7]);
}

extern "C" void kernel_launch(void* const* d_in, const int* in_sizes, int n_in,
                              void* d_out, int out_size, void* d_ws, size_t ws_size,
                              hipStream_t stream) {
  const float* hidden   = (const float*)d_in[0];
  const float* prior_w  = (const float*)d_in[1];
  const float* prior_b  = (const float*)d_in[2];
  const float* latent_w = (const float*)d_in[3];
  const float* latent_b = (const float*)d_in[4];
  const float* output_w = (const float*)d_in[5];
  const float* output_b = (const float*)d_in[6];
  float* out = (float*)d_out;

  char* ws = (char*)d_ws;
  size_t off = 0;
  auto alloc = [&](size_t bytes) -> void* {
    void* p = ws + off;
    off += (bytes + 255) & ~(size_t)255;
    return p;
  };
  f16* hidden_h = (f16*)alloc((size_t)T_TOK * H_DIM * 2);          // [8192][1024]
  f16* lw_t     = (f16*)alloc((size_t)NHEAD * H_DIM * H_DIM * 2);  // [8192][1024]
  f16* ow_t     = (f16*)alloc((size_t)V_DIM * H_DIM * 2);          // [2048][1024]
  float* prior  = (float*)alloc((size_t)T_TOK * NHEAD * 4);

  // tc=2048: (a) logits chunk (64 MiB) L3-resident between GEMM2 and softmax;
  // (b) GEMM1 grid (32,8): XCD swizzle gives each XCD ONE m-row x 32 n-tiles
  //     -> lw_t read once per XCD (128 MiB chip-wide, 4x less than tc=8192);
  // (c) GEMM2 B (ow_t, 4 MiB) fully L2-resident per XCD.
  int tc = 2048;
  while (tc > 256) {
    size_t need = off + (size_t)tc * NHEAD * H_DIM * 2 + 256 +
                  (size_t)tc * NHEAD * V_DIM * 2 + 256;
    if (need <= ws_size) break;
    tc >>= 1;
  }
  f16* latent_h = (f16*)alloc((size_t)tc * NHEAD * H_DIM * 2);  // [tc*8][1024]
  f16* logits_h = (f16*)alloc((size_t)tc * NHEAD * V_DIM * 2);  // [tc*8][2048]

  // prep passes
  k_convert<<<(T_TOK * H_DIM / 4 + 255) / 256, 256, 0, stream>>>(
      hidden, hidden_h, T_TOK * H_DIM / 4);
  k_transpose<<<dim3(NHEAD * H_DIM / 32, H_DIM / 32), dim3(32, 8), 0, stream>>>(
      latent_w, lw_t, H_DIM, NHEAD * H_DIM);
  k_transpose<<<dim3(V_DIM / 32, H_DIM / 32), dim3(32, 8), 0, stream>>>(
      output_w, ow_t, H_DIM, V_DIM);
  k_prior<<<T_TOK / 4, 256, 0, stream>>>(hidden, prior_w, prior_b, prior);

  const int nchunk = T_TOK / tc;
  for (int c = 0; c < nchunk; ++c) {
    const f16* Ah = hidden_h + (size_t)c * tc * H_DIM;
    // latent = tanh(hidden @ latent_w + latent_b), stored [tc*8][1024] f16
    k_gemm<1><<<dim3(NHEAD * H_DIM / 256, tc / 256), 512, 0, stream>>>(
        Ah, lw_t, latent_b, latent_h, tc, NHEAD * H_DIM, H_DIM);
    // logits = latent @ output_w + output_b, stored [tc*8][2048] f16
    k_gemm<0><<<dim3(V_DIM / 256, tc * NHEAD / 256), 512, 0, stream>>>(
        latent_h, ow_t, output_b, logits_h, tc * NHEAD, V_DIM, H_DIM);
    // softmax over V per head, prior-weighted sum over heads
    k_softmax<<<tc, 256, 0, stream>>>(logits_h, prior + (size_t)c * tc * NHEAD,
                                      out + (size_t)c * tc * V_DIM);
  }
}

// Round 7
// 594.682 us; speedup vs baseline: 1.0468x; 1.0375x over previous
//
#include <hip/hip_runtime.h>
#include <hip/hip_bf16.h>
#include <stdint.h>

typedef _Float16 f16;
typedef _Float16 f16x8 __attribute__((ext_vector_type(8)));
typedef _Float16 f16x4 __attribute__((ext_vector_type(4)));
typedef float f32x4 __attribute__((ext_vector_type(4)));
typedef float f32x16 __attribute__((ext_vector_type(16)));

#define T_TOK 8192
#define H_DIM 1024
#define NHEAD 8
#define V_DIM 2048

// global -> LDS direct load, 16B per lane. LDS dest = wave-uniform base + lane*16.
__device__ __forceinline__ void gload16(const void* g, void* l) {
  __builtin_amdgcn_global_load_lds(
      (const __attribute__((address_space(1))) void*)(uintptr_t)g,
      (__attribute__((address_space(3))) void*)(unsigned)(uintptr_t)l,
      16, 0, 0);
}

__device__ __forceinline__ float fast_tanh(float x) {
  float xc = fminf(fmaxf(x, -12.f), 12.f);
  float e = __expf(2.f * xc);
  return (e - 1.f) / (e + 1.f);
}

// Stage one half-tile (128 rows x 64 f16 = 16KB) with 2 global_load_lds.
__device__ __forceinline__ void stage_half(const f16* __restrict__ gRowBase,
                                           char* ldsHalf, int tid, int sl8,
                                           int Kd) {
  const int srow = tid >> 3;
  char* wuni = ldsHalf + ((tid >> 6) << 10);  // wave-uniform base
  gload16(gRowBase + (size_t)srow * Kd + sl8, wuni);
  gload16(gRowBase + (size_t)(srow + 64) * Kd + sl8, wuni + 8192);
}

// ---------- 256x256x64 pipelined 4-phase GEMM, 32x32x16 MFMA ----------
// [R4-proven 1.83 PF @ tc=8192 — inner loop untouched since]
// NMAJ: XCD-swizzle orientation. m-major (NMAJ=0): each XCD gets an m-slice x
// all n (use when B is L2-small). n-major (NMAJ=1): each XCD gets an n-slice x
// all m -> B-slice L2-resident (use when B is large, e.g. GEMM1's 16 MiB).
template <int TANH, int NMAJ>
__global__ __launch_bounds__(512, 2) void k_gemm(const f16* __restrict__ A,
                                                 const f16* __restrict__ Bt,
                                                 const float* __restrict__ bias,
                                                 f16* __restrict__ C,
                                                 int M, int N, int K) {
  __shared__ __align__(16) f16 sA[2][16384];
  __shared__ __align__(16) f16 sB[2][16384];
  const int tid = threadIdx.x;
  const int lane = tid & 63;
  const int wid = tid >> 6;
  const int wr = wid >> 2, wc = wid & 3;
  const int gx = gridDim.x, gy = gridDim.y;
  const int id = blockIdx.y * gx + blockIdx.x;
  const int cpx = (gx * gy) >> 3;
  const int sw = (id & 7) * cpx + (id >> 3);
  int m0, n0;
  if (NMAJ) {
    n0 = (sw / gy) * 256;
    m0 = (sw % gy) * 256;
  } else {
    m0 = (sw / gx) * 256;
    n0 = (sw % gx) * 256;
  }
  const int NT = K >> 6;  // NT even (K % 128 == 0)
  const int sl8 = ((tid & 7) ^ ((tid >> 3) & 7)) << 3;  // staging src col (f16)
  const int rr31 = lane & 31;   // A/B fragment row (m or n within 32)
  const int hi = lane >> 5;     // k-half selector
  const int l7 = lane & 7;      // row&7 for XOR slot swizzle

  const f16* Ag = A + (size_t)m0 * K;
  const f16* Bg = Bt + (size_t)n0 * K;
  char* sAb = (char*)&sA[0][0];
  char* sBb = (char*)&sB[0][0];

  // prologue: tile0 A+B -> buf0, tile1 B -> buf1
  stage_half(Ag, sAb, tid, sl8, K);
  stage_half(Ag + (size_t)128 * K, sAb + 16384, tid, sl8, K);
  stage_half(Bg, sBb, tid, sl8, K);
  stage_half(Bg + (size_t)128 * K, sBb + 16384, tid, sl8, K);
  stage_half(Bg + 64, sBb + 32768, tid, sl8, K);
  stage_half(Bg + (size_t)128 * K + 64, sBb + 32768 + 16384, tid, sl8, K);
  asm volatile("s_waitcnt vmcnt(4)" ::: "memory");  // tile0 A+B resident
  __builtin_amdgcn_s_barrier();
  __builtin_amdgcn_sched_barrier(0);

  f32x16 acc[4][2] = {};
  f16x8 af0[4], af1[4], bf[2][4];

#define LDA_SET(dst, base, q)                                                  \
  {                                                                            \
    _Pragma("unroll") for (int mi = 0; mi < 4; ++mi) {                         \
      dst[mi] = *(const f16x8*)((base) + wr * 16384 + mi * 4096 + rr31 * 128 + \
                                (((2 * (q) + hi) ^ l7) << 4));                 \
    }                                                                          \
  }
#define LDB(base)                                                              \
  {                                                                            \
    _Pragma("unroll") for (int n = 0; n < 2; ++n) {                            \
      _Pragma("unroll") for (int ks = 0; ks < 4; ++ks) {                       \
        bf[n][ks] = *(const f16x8*)((base) + wc * 8192 + n * 4096 +            \
                                    rr31 * 128 + (((2 * ks + hi) ^ l7) << 4)); \
      }                                                                        \
    }                                                                          \
  }
#define MFMA8(ks, S)                                                           \
  {                                                                            \
    __builtin_amdgcn_s_setprio(1);                                             \
    _Pragma("unroll") for (int mi = 0; mi < 4; ++mi) {                         \
      _Pragma("unroll") for (int n = 0; n < 2; ++n) {                          \
        acc[mi][n] = __builtin_amdgcn_mfma_f32_32x32x16_f16(                   \
            S[mi], bf[n][ks], acc[mi][n], 0, 0, 0);                            \
      }                                                                        \
    }                                                                          \
    __builtin_amdgcn_s_setprio(0);                                             \
  }

  // preload k-step 0 fragments of tile 0
  LDA_SET(af0, sAb, 0);

#define HALF(tt, bc)                                                           \
  {                                                                            \
    const char* cA = sAb + (bc)*32768;                                         \
    const char* cB = sBb + (bc)*32768;                                         \
    char* nA = sAb + ((bc) ^ 1) * 32768;                                       \
    char* nB = sBb + (bc)*32768;                                               \
    const int ktA = ((tt) + 1) << 6, ktB = ((tt) + 2) << 6;                    \
    const bool doA = (tt) + 1 < NT, doB = (tt) + 2 < NT;                       \
    /* ph0 */                                                                  \
    if (doA) stage_half(Ag + ktA, nA, tid, sl8, K);                            \
    LDB(cB);                                                                   \
    LDA_SET(af1, cA, 1);                                                       \
    __builtin_amdgcn_sched_barrier(0);                                         \
    MFMA8(0, af0);                                                             \
    __builtin_amdgcn_s_barrier();                                              \
    /* ph1 */                                                                  \
    if (doA) stage_half(Ag + (size_t)128 * K + ktA, nA + 16384, tid, sl8, K);  \
    LDA_SET(af0, cA, 2);                                                       \
    __builtin_amdgcn_sched_barrier(0);                                         \
    MFMA8(1, af1);                                                             \
    __builtin_amdgcn_s_barrier();                                              \
    /* ph2 */                                                                  \
    if (doB) stage_half(Bg + ktB, nB, tid, sl8, K);                            \
    LDA_SET(af1, cA, 3);                                                       \
    __builtin_amdgcn_sched_barrier(0);                                         \
    MFMA8(2, af0);                                                             \
    __builtin_amdgcn_s_barrier();                                              \
    /* ph3: counted vmcnt; preload next tile ks0 after barrier */              \
    if (doB) stage_half(Bg + (size_t)128 * K + ktB, nB + 16384, tid, sl8, K);  \
    if (doB) {                                                                 \
      asm volatile("s_waitcnt vmcnt(4)" ::: "memory");                         \
    } else {                                                                   \
      asm volatile("s_waitcnt vmcnt(0)" ::: "memory");                         \
    }                                                                          \
    __builtin_amdgcn_s_barrier();                                              \
    __builtin_amdgcn_sched_barrier(0);                                         \
    if (doA) LDA_SET(af0, sAb + ((bc) ^ 1) * 32768, 0);                        \
    __builtin_amdgcn_sched_barrier(0);                                         \
    MFMA8(3, af1);                                                             \
  }

#pragma unroll 1
  for (int T = 0; T < NT; T += 2) {
    HALF(T, 0);
    HALF(T + 1, 1);
  }
#undef HALF
#undef LDA_SET
#undef LDB
#undef MFMA8

  // epilogue: 32x32 D layout: col = lane&31, row = (reg&3) + 8*(reg>>2) + 4*hi
  const int ccol0 = n0 + wc * 64 + rr31;
  float bv[2];
#pragma unroll
  for (int n = 0; n < 2; ++n) bv[n] = bias[ccol0 + n * 32];
#pragma unroll
  for (int mi = 0; mi < 4; ++mi) {
#pragma unroll
    for (int rq = 0; rq < 4; ++rq) {
#pragma unroll
      for (int r2 = 0; r2 < 4; ++r2) {
        const int row = m0 + wr * 128 + mi * 32 + r2 + 8 * rq + 4 * hi;
        f16* Crow = C + (size_t)row * N;
#pragma unroll
        for (int n = 0; n < 2; ++n) {
          float v = acc[mi][n][rq * 4 + r2] + bv[n];
          if (TANH) v = fast_tanh(v);
          Crow[ccol0 + n * 32] = (f16)v;
        }
      }
    }
  }
}

// ---------- fp32 -> fp16 elementwise convert ----------
__global__ __launch_bounds__(256) void k_convert(const float* __restrict__ in,
                                                 f16* __restrict__ out, int n4) {
  int i = blockIdx.x * blockDim.x + threadIdx.x;
  if (i >= n4) return;
  const float4 v = ((const float4*)in)[i];
  f16x4 o;
  o[0] = (f16)v.x; o[1] = (f16)v.y; o[2] = (f16)v.z; o[3] = (f16)v.w;
  ((f16x4*)out)[i] = o;
}

// ---------- fp32 [R][C] -> fp16 [C][R] transpose-convert ----------
__global__ void k_transpose(const float* __restrict__ in, f16* __restrict__ out,
                            int R, int C) {
  __shared__ f16 tile[32][33];
  int c0 = blockIdx.x * 32, r0 = blockIdx.y * 32;
  for (int j = threadIdx.y; j < 32; j += 8)
    tile[j][threadIdx.x] = (f16)in[(size_t)(r0 + j) * C + (c0 + threadIdx.x)];
  __syncthreads();
  for (int j = threadIdx.y; j < 32; j += 8)
    out[(size_t)(c0 + j) * R + (r0 + threadIdx.x)] = tile[threadIdx.x][j];
}

// ---------- prior: sigmoid(hidden @ prior_w + b), renormalized over heads ----------
__global__ __launch_bounds__(256) void k_prior(const float* __restrict__ hidden,
                                               const float* __restrict__ pw,
                                               const float* __restrict__ pb,
                                               float* __restrict__ prior) {
  const int wid = threadIdx.x >> 6, lane = threadIdx.x & 63;
  const int t = blockIdx.x * 4 + wid;
  float acc[NHEAD] = {0.f, 0.f, 0.f, 0.f, 0.f, 0.f, 0.f, 0.f};
  const float* hrow = hidden + (size_t)t * H_DIM;
  for (int k = lane; k < H_DIM; k += 64) {
    float x = hrow[k];
    const float* wr = pw + k * NHEAD;
#pragma unroll
    for (int h = 0; h < NHEAD; ++h) acc[h] += x * wr[h];
  }
#pragma unroll
  for (int h = 0; h < NHEAD; ++h) {
#pragma unroll
    for (int off = 32; off >= 1; off >>= 1) acc[h] += __shfl_xor(acc[h], off);
  }
  if (lane == 0) {
    float p[NHEAD], s = 0.f;
#pragma unroll
    for (int h = 0; h < NHEAD; ++h) {
      p[h] = 1.f / (1.f + __expf(-(acc[h] + pb[h])));
      s += p[h];
    }
    float inv = 1.f / (s + 1e-8f);
#pragma unroll
    for (int h = 0; h < NHEAD; ++h) prior[t * NHEAD + h] = p[h] * inv;
  }
}

// ---------- batched softmax: all 8 heads in flight, 2 barriers/block -------
// Per block = 1 token. Thread covers v = tid*8..tid*8+8 for ALL heads.
// Loads issue together (8 outstanding); per-wave reductions barrier-free;
// one barrier for cross-wave max, one for cross-wave sum.
__global__ __launch_bounds__(256) void k_softmax(const f16* __restrict__ logits,
                                                 const float* __restrict__ prior,
                                                 float* __restrict__ out) {
  __shared__ float redmx[NHEAD * 4];
  __shared__ float redsm[NHEAD * 4];
  const int t = blockIdx.x;
  const int tid = threadIdx.x, lane = tid & 63, wid = tid >> 6;
  const f16* base = logits + (size_t)t * NHEAD * V_DIM + tid * 8;

  f16x8 x[NHEAD];
#pragma unroll
  for (int h = 0; h < NHEAD; ++h) x[h] = *(const f16x8*)(base + h * V_DIM);

  float xv[NHEAD][8];
  float mxl[NHEAD];
#pragma unroll
  for (int h = 0; h < NHEAD; ++h) {
    mxl[h] = -1e30f;
#pragma unroll
    for (int j = 0; j < 8; ++j) {
      xv[h][j] = (float)x[h][j];
      mxl[h] = fmaxf(mxl[h], xv[h][j]);
    }
  }
#pragma unroll
  for (int h = 0; h < NHEAD; ++h) {
#pragma unroll
    for (int off = 32; off >= 1; off >>= 1)
      mxl[h] = fmaxf(mxl[h], __shfl_xor(mxl[h], off));
  }
  if (lane == 0) {
#pragma unroll
    for (int h = 0; h < NHEAD; ++h) redmx[h * 4 + wid] = mxl[h];
  }
  __syncthreads();

  float sml[NHEAD];
#pragma unroll
  for (int h = 0; h < NHEAD; ++h) {
    const float mx = fmaxf(fmaxf(redmx[h * 4 + 0], redmx[h * 4 + 1]),
                           fmaxf(redmx[h * 4 + 2], redmx[h * 4 + 3]));
    float s = 0.f;
#pragma unroll
    for (int j = 0; j < 8; ++j) {
      xv[h][j] = __expf(xv[h][j] - mx);
      s += xv[h][j];
    }
    sml[h] = s;
  }
#pragma unroll
  for (int h = 0; h < NHEAD; ++h) {
#pragma unroll
    for (int off = 32; off >= 1; off >>= 1) sml[h] += __shfl_xor(sml[h], off);
  }
  if (lane == 0) {
#pragma unroll
    for (int h = 0; h < NHEAD; ++h) redsm[h * 4 + wid] = sml[h];
  }
  __syncthreads();

  float oa[8] = {0.f, 0.f, 0.f, 0.f, 0.f, 0.f, 0.f, 0.f};
#pragma unroll
  for (int h = 0; h < NHEAD; ++h) {
    const float s = redsm[h * 4 + 0] + redsm[h * 4 + 1] + redsm[h * 4 + 2] +
                    redsm[h * 4 + 3];
    const float coef = prior[t * NHEAD + h] / s;
#pragma unroll
    for (int j = 0; j < 8; ++j) oa[j] += coef * xv[h][j];
  }
  float4* op = (float4*)(out + (size_t)t * V_DIM + tid * 8);
  op[0] = make_float4(oa[0], oa[1], oa[2], oa[3]);
  op[1] = make_float4(oa[4], oa[5], oa[6], oa[7]);
}

extern "C" void kernel_launch(void* const* d_in, const int* in_sizes, int n_in,
                              void* d_out, int out_size, void* d_ws, size_t ws_size,
                              hipStream_t stream) {
  const float* hidden   = (const float*)d_in[0];
  const float* prior_w  = (const float*)d_in[1];
  const float* prior_b  = (const float*)d_in[2];
  const float* latent_w = (const float*)d_in[3];
  const float* latent_b = (const float*)d_in[4];
  const float* output_w = (const float*)d_in[5];
  const float* output_b = (const float*)d_in[6];
  float* out = (float*)d_out;

  char* ws = (char*)d_ws;
  size_t off = 0;
  auto alloc = [&](size_t bytes) -> void* {
    void* p = ws + off;
    off += (bytes + 255) & ~(size_t)255;
    return p;
  };
  f16* hidden_h = (f16*)alloc((size_t)T_TOK * H_DIM * 2);          // [8192][1024]
  f16* lw_t     = (f16*)alloc((size_t)NHEAD * H_DIM * H_DIM * 2);  // [8192][1024]
  f16* ow_t     = (f16*)alloc((size_t)V_DIM * H_DIM * 2);          // [2048][1024]
  float* prior  = (float*)alloc((size_t)T_TOK * NHEAD * 4);

  // tc=8192 (R6 proved per-work GEMM is 2x faster at large grids; R4 proved
  // ws fits). Fallback halving only if ws is unexpectedly small.
  int tc = T_TOK;
  while (tc > 256) {
    size_t need = off + (size_t)tc * NHEAD * H_DIM * 2 + 256 +
                  (size_t)tc * NHEAD * V_DIM * 2 + 256;
    if (need <= ws_size) break;
    tc >>= 1;
  }
  f16* latent_h = (f16*)alloc((size_t)tc * NHEAD * H_DIM * 2);  // [tc*8][1024]
  f16* logits_h = (f16*)alloc((size_t)tc * NHEAD * V_DIM * 2);  // [tc*8][2048]

  // prep passes
  k_convert<<<(T_TOK * H_DIM / 4 + 255) / 256, 256, 0, stream>>>(
      hidden, hidden_h, T_TOK * H_DIM / 4);
  k_transpose<<<dim3(NHEAD * H_DIM / 32, H_DIM / 32), dim3(32, 8), 0, stream>>>(
      latent_w, lw_t, H_DIM, NHEAD * H_DIM);
  k_transpose<<<dim3(V_DIM / 32, H_DIM / 32), dim3(32, 8), 0, stream>>>(
      output_w, ow_t, H_DIM, V_DIM);
  k_prior<<<T_TOK / 4, 256, 0, stream>>>(hidden, prior_w, prior_b, prior);

  const int nchunk = T_TOK / tc;
  for (int c = 0; c < nchunk; ++c) {
    const f16* Ah = hidden_h + (size_t)c * tc * H_DIM;
    // GEMM1: latent = tanh(hidden @ latent_w + b). B = lw_t (16 MiB) ->
    // n-major XCD swizzle so each XCD's B-slice (2 MiB) is L2-resident.
    k_gemm<1, 1><<<dim3(NHEAD * H_DIM / 256, tc / 256), 512, 0, stream>>>(
        Ah, lw_t, latent_b, latent_h, tc, NHEAD * H_DIM, H_DIM);
    // GEMM2: logits = latent @ output_w + b. B = ow_t (4 MiB, L2-fits) ->
    // m-major swizzle (R4-proven 1.83 PF).
    k_gemm<0, 0><<<dim3(V_DIM / 256, tc * NHEAD / 256), 512, 0, stream>>>(
        latent_h, ow_t, output_b, logits_h, tc * NHEAD, V_DIM, H_DIM);
    // batched softmax over V per head + prior-weighted combine
    k_softmax<<<tc, 256, 0, stream>>>(logits_h, prior + (size_t)c * tc * NHEAD,
                                      out + (size_t)c * tc * V_DIM);
  }
}

// Round 8
// 572.606 us; speedup vs baseline: 1.0871x; 1.0386x over previous
//
#include <hip/hip_runtime.h>
#include <hip/hip_bf16.h>
#include <stdint.h>

typedef _Float16 f16;
typedef _Float16 f16x8 __attribute__((ext_vector_type(8)));
typedef _Float16 f16x4 __attribute__((ext_vector_type(4)));
typedef float f32x4 __attribute__((ext_vector_type(4)));
typedef float f32x16 __attribute__((ext_vector_type(16)));

#define T_TOK 8192
#define H_DIM 1024
#define NHEAD 8
#define V_DIM 2048

// global -> LDS direct load, 16B per lane. LDS dest = wave-uniform base + lane*16.
__device__ __forceinline__ void gload16(const void* g, void* l) {
  __builtin_amdgcn_global_load_lds(
      (const __attribute__((address_space(1))) void*)(uintptr_t)g,
      (__attribute__((address_space(3))) void*)(unsigned)(uintptr_t)l,
      16, 0, 0);
}

__device__ __forceinline__ float fast_tanh(float x) {
  float xc = fminf(fmaxf(x, -12.f), 12.f);
  float e = __expf(2.f * xc);
  return (e - 1.f) / (e + 1.f);
}

// Stage one half-tile (128 rows x 64 f16 = 16KB) with 2 global_load_lds.
__device__ __forceinline__ void stage_half(const f16* __restrict__ gRowBase,
                                           char* ldsHalf, int tid, int sl8,
                                           int Kd) {
  const int srow = tid >> 3;
  char* wuni = ldsHalf + ((tid >> 6) << 10);  // wave-uniform base
  gload16(gRowBase + (size_t)srow * Kd + sl8, wuni);
  gload16(gRowBase + (size_t)(srow + 64) * Kd + sl8, wuni + 8192);
}

// ---------- 256x256x64 pipelined 4-phase GEMM, 32x32x16 MFMA ----------
// [R4-proven 1.83 PF — inner loop untouched since R4]
template <int TANH, int NMAJ>
__global__ __launch_bounds__(512, 2) void k_gemm(const f16* __restrict__ A,
                                                 const f16* __restrict__ Bt,
                                                 const float* __restrict__ bias,
                                                 f16* __restrict__ C,
                                                 int M, int N, int K) {
  __shared__ __align__(16) f16 sA[2][16384];
  __shared__ __align__(16) f16 sB[2][16384];
  const int tid = threadIdx.x;
  const int lane = tid & 63;
  const int wid = tid >> 6;
  const int wr = wid >> 2, wc = wid & 3;
  const int gx = gridDim.x, gy = gridDim.y;
  const int id = blockIdx.y * gx + blockIdx.x;
  const int cpx = (gx * gy) >> 3;
  const int sw = (id & 7) * cpx + (id >> 3);
  int m0, n0;
  if (NMAJ) {
    n0 = (sw / gy) * 256;
    m0 = (sw % gy) * 256;
  } else {
    m0 = (sw / gx) * 256;
    n0 = (sw % gx) * 256;
  }
  const int NT = K >> 6;  // NT even (K % 128 == 0)
  const int sl8 = ((tid & 7) ^ ((tid >> 3) & 7)) << 3;  // staging src col (f16)
  const int rr31 = lane & 31;   // A/B fragment row (m or n within 32)
  const int hi = lane >> 5;     // k-half selector
  const int l7 = lane & 7;      // row&7 for XOR slot swizzle

  const f16* Ag = A + (size_t)m0 * K;
  const f16* Bg = Bt + (size_t)n0 * K;
  char* sAb = (char*)&sA[0][0];
  char* sBb = (char*)&sB[0][0];

  // prologue: tile0 A+B -> buf0, tile1 B -> buf1
  stage_half(Ag, sAb, tid, sl8, K);
  stage_half(Ag + (size_t)128 * K, sAb + 16384, tid, sl8, K);
  stage_half(Bg, sBb, tid, sl8, K);
  stage_half(Bg + (size_t)128 * K, sBb + 16384, tid, sl8, K);
  stage_half(Bg + 64, sBb + 32768, tid, sl8, K);
  stage_half(Bg + (size_t)128 * K + 64, sBb + 32768 + 16384, tid, sl8, K);
  asm volatile("s_waitcnt vmcnt(4)" ::: "memory");  // tile0 A+B resident
  __builtin_amdgcn_s_barrier();
  __builtin_amdgcn_sched_barrier(0);

  f32x16 acc[4][2] = {};
  f16x8 af0[4], af1[4], bf[2][4];

#define LDA_SET(dst, base, q)                                                  \
  {                                                                            \
    _Pragma("unroll") for (int mi = 0; mi < 4; ++mi) {                         \
      dst[mi] = *(const f16x8*)((base) + wr * 16384 + mi * 4096 + rr31 * 128 + \
                                (((2 * (q) + hi) ^ l7) << 4));                 \
    }                                                                          \
  }
#define LDB(base)                                                              \
  {                                                                            \
    _Pragma("unroll") for (int n = 0; n < 2; ++n) {                            \
      _Pragma("unroll") for (int ks = 0; ks < 4; ++ks) {                       \
        bf[n][ks] = *(const f16x8*)((base) + wc * 8192 + n * 4096 +            \
                                    rr31 * 128 + (((2 * ks + hi) ^ l7) << 4)); \
      }                                                                        \
    }                                                                          \
  }
#define MFMA8(ks, S)                                                           \
  {                                                                            \
    __builtin_amdgcn_s_setprio(1);                                             \
    _Pragma("unroll") for (int mi = 0; mi < 4; ++mi) {                         \
      _Pragma("unroll") for (int n = 0; n < 2; ++n) {                          \
        acc[mi][n] = __builtin_amdgcn_mfma_f32_32x32x16_f16(                   \
            S[mi], bf[n][ks], acc[mi][n], 0, 0, 0);                            \
      }                                                                        \
    }                                                                          \
    __builtin_amdgcn_s_setprio(0);                                             \
  }

  // preload k-step 0 fragments of tile 0
  LDA_SET(af0, sAb, 0);

#define HALF(tt, bc)                                                           \
  {                                                                            \
    const char* cA = sAb + (bc)*32768;                                         \
    const char* cB = sBb + (bc)*32768;                                         \
    char* nA = sAb + ((bc) ^ 1) * 32768;                                       \
    char* nB = sBb + (bc)*32768;                                               \
    const int ktA = ((tt) + 1) << 6, ktB = ((tt) + 2) << 6;                    \
    const bool doA = (tt) + 1 < NT, doB = (tt) + 2 < NT;                       \
    /* ph0 */                                                                  \
    if (doA) stage_half(Ag + ktA, nA, tid, sl8, K);                            \
    LDB(cB);                                                                   \
    LDA_SET(af1, cA, 1);                                                       \
    __builtin_amdgcn_sched_barrier(0);                                         \
    MFMA8(0, af0);                                                             \
    __builtin_amdgcn_s_barrier();                                              \
    /* ph1 */                                                                  \
    if (doA) stage_half(Ag + (size_t)128 * K + ktA, nA + 16384, tid, sl8, K);  \
    LDA_SET(af0, cA, 2);                                                       \
    __builtin_amdgcn_sched_barrier(0);                                         \
    MFMA8(1, af1);                                                             \
    __builtin_amdgcn_s_barrier();                                              \
    /* ph2 */                                                                  \
    if (doB) stage_half(Bg + ktB, nB, tid, sl8, K);                            \
    LDA_SET(af1, cA, 3);                                                       \
    __builtin_amdgcn_sched_barrier(0);                                         \
    MFMA8(2, af0);                                                             \
    __builtin_amdgcn_s_barrier();                                              \
    /* ph3: counted vmcnt; preload next tile ks0 after barrier */              \
    if (doB) stage_half(Bg + (size_t)128 * K + ktB, nB + 16384, tid, sl8, K);  \
    if (doB) {                                                                 \
      asm volatile("s_waitcnt vmcnt(4)" ::: "memory");                         \
    } else {                                                                   \
      asm volatile("s_waitcnt vmcnt(0)" ::: "memory");                         \
    }                                                                          \
    __builtin_amdgcn_s_barrier();                                              \
    __builtin_amdgcn_sched_barrier(0);                                         \
    if (doA) LDA_SET(af0, sAb + ((bc) ^ 1) * 32768, 0);                        \
    __builtin_amdgcn_sched_barrier(0);                                         \
    MFMA8(3, af1);                                                             \
  }

#pragma unroll 1
  for (int T = 0; T < NT; T += 2) {
    HALF(T, 0);
    HALF(T + 1, 1);
  }
#undef HALF
#undef LDA_SET
#undef LDB
#undef MFMA8

  // epilogue: 32x32 D layout: col = lane&31, row = (reg&3) + 8*(reg>>2) + 4*hi
  const int ccol0 = n0 + wc * 64 + rr31;
  float bv[2];
#pragma unroll
  for (int n = 0; n < 2; ++n) bv[n] = bias[ccol0 + n * 32];
#pragma unroll
  for (int mi = 0; mi < 4; ++mi) {
#pragma unroll
    for (int rq = 0; rq < 4; ++rq) {
#pragma unroll
      for (int r2 = 0; r2 < 4; ++r2) {
        const int row = m0 + wr * 128 + mi * 32 + r2 + 8 * rq + 4 * hi;
        f16* Crow = C + (size_t)row * N;
#pragma unroll
        for (int n = 0; n < 2; ++n) {
          float v = acc[mi][n][rq * 4 + r2] + bv[n];
          if (TANH) v = fast_tanh(v);
          Crow[ccol0 + n * 32] = (f16)v;
        }
      }
    }
  }
}

// ---------- fp32 -> fp16 elementwise convert ----------
__global__ __launch_bounds__(256) void k_convert(const float* __restrict__ in,
                                                 f16* __restrict__ out, int n4) {
  int i = blockIdx.x * blockDim.x + threadIdx.x;
  if (i >= n4) return;
  const float4 v = ((const float4*)in)[i];
  f16x4 o;
  o[0] = (f16)v.x; o[1] = (f16)v.y; o[2] = (f16)v.z; o[3] = (f16)v.w;
  ((f16x4*)out)[i] = o;
}

// ---------- fp32 [R][C] -> fp16 [C][R] transpose-convert, 64x64 tiles -------
// float4 global reads (256B/16-lane row), f16x4 writes, pad-66 LDS.
__global__ __launch_bounds__(256) void k_transpose(const float* __restrict__ in,
                                                   f16* __restrict__ out,
                                                   int R, int C) {
  __shared__ f16 tile[64][66];
  const int c0 = blockIdx.x * 64, r0 = blockIdx.y * 64;
  const int tid = threadIdx.x;
  const int tr = tid >> 4;          // 0..15
  const int tc4 = (tid & 15) * 4;   // 0..60
#pragma unroll
  for (int i = 0; i < 4; ++i) {
    const int r = tr + i * 16;
    const float4 v = *(const float4*)&in[(size_t)(r0 + r) * C + c0 + tc4];
    tile[tc4 + 0][r] = (f16)v.x;
    tile[tc4 + 1][r] = (f16)v.y;
    tile[tc4 + 2][r] = (f16)v.z;
    tile[tc4 + 3][r] = (f16)v.w;
  }
  __syncthreads();
  const int oc = tid >> 2;          // 0..63
  const int or4 = (tid & 3) * 16;   // 0,16,32,48
#pragma unroll
  for (int i = 0; i < 4; ++i) {
    f16x4 w;
    w[0] = tile[oc][or4 + i * 4 + 0];
    w[1] = tile[oc][or4 + i * 4 + 1];
    w[2] = tile[oc][or4 + i * 4 + 2];
    w[3] = tile[oc][or4 + i * 4 + 3];
    *(f16x4*)&out[(size_t)(c0 + oc) * R + r0 + or4 + i * 4] = w;
  }
}

// ---------- prior: sigmoid(hidden @ prior_w + b), renormalized over heads ----------
__global__ __launch_bounds__(256) void k_prior(const float* __restrict__ hidden,
                                               const float* __restrict__ pw,
                                               const float* __restrict__ pb,
                                               float* __restrict__ prior) {
  const int wid = threadIdx.x >> 6, lane = threadIdx.x & 63;
  const int t = blockIdx.x * 4 + wid;
  float acc[NHEAD] = {0.f, 0.f, 0.f, 0.f, 0.f, 0.f, 0.f, 0.f};
  const float* hrow = hidden + (size_t)t * H_DIM;
  for (int k = lane; k < H_DIM; k += 64) {
    float x = hrow[k];
    const float* wr = pw + k * NHEAD;
#pragma unroll
    for (int h = 0; h < NHEAD; ++h) acc[h] += x * wr[h];
  }
#pragma unroll
  for (int h = 0; h < NHEAD; ++h) {
#pragma unroll
    for (int off = 32; off >= 1; off >>= 1) acc[h] += __shfl_xor(acc[h], off);
  }
  if (lane == 0) {
    float p[NHEAD], s = 0.f;
#pragma unroll
    for (int h = 0; h < NHEAD; ++h) {
      p[h] = 1.f / (1.f + __expf(-(acc[h] + pb[h])));
      s += p[h];
    }
    float inv = 1.f / (s + 1e-8f);
#pragma unroll
    for (int h = 0; h < NHEAD; ++h) prior[t * NHEAD + h] = p[h] * inv;
  }
}

// ---------- softmax without max-pass: logits bounded (|x| <~ 6), f32 exp is
// safe unsubtracted (clamp 50 for paranoia). One barrier per block.
__global__ __launch_bounds__(256) void k_softmax(const f16* __restrict__ logits,
                                                 const float* __restrict__ prior,
                                                 float* __restrict__ out) {
  __shared__ float redsm[NHEAD * 4];
  const int t = blockIdx.x;
  const int tid = threadIdx.x, lane = tid & 63, wid = tid >> 6;
  const f16* base = logits + (size_t)t * NHEAD * V_DIM + tid * 8;

  f16x8 x[NHEAD];
#pragma unroll
  for (int h = 0; h < NHEAD; ++h) x[h] = *(const f16x8*)(base + h * V_DIM);

  float xv[NHEAD][8];
  float sml[NHEAD];
#pragma unroll
  for (int h = 0; h < NHEAD; ++h) {
    float s = 0.f;
#pragma unroll
    for (int j = 0; j < 8; ++j) {
      xv[h][j] = __expf(fminf((float)x[h][j], 50.f));
      s += xv[h][j];
    }
    sml[h] = s;
  }
#pragma unroll
  for (int h = 0; h < NHEAD; ++h) {
#pragma unroll
    for (int off = 32; off >= 1; off >>= 1) sml[h] += __shfl_xor(sml[h], off);
  }
  if (lane == 0) {
#pragma unroll
    for (int h = 0; h < NHEAD; ++h) redsm[h * 4 + wid] = sml[h];
  }
  __syncthreads();

  float oa[8] = {0.f, 0.f, 0.f, 0.f, 0.f, 0.f, 0.f, 0.f};
#pragma unroll
  for (int h = 0; h < NHEAD; ++h) {
    const float s = redsm[h * 4 + 0] + redsm[h * 4 + 1] + redsm[h * 4 + 2] +
                    redsm[h * 4 + 3];
    const float coef = prior[t * NHEAD + h] / s;
#pragma unroll
    for (int j = 0; j < 8; ++j) oa[j] += coef * xv[h][j];
  }
  float4* op = (float4*)(out + (size_t)t * V_DIM + tid * 8);
  op[0] = make_float4(oa[0], oa[1], oa[2], oa[3]);
  op[1] = make_float4(oa[4], oa[5], oa[6], oa[7]);
}

extern "C" void kernel_launch(void* const* d_in, const int* in_sizes, int n_in,
                              void* d_out, int out_size, void* d_ws, size_t ws_size,
                              hipStream_t stream) {
  const float* hidden   = (const float*)d_in[0];
  const float* prior_w  = (const float*)d_in[1];
  const float* prior_b  = (const float*)d_in[2];
  const float* latent_w = (const float*)d_in[3];
  const float* latent_b = (const float*)d_in[4];
  const float* output_w = (const float*)d_in[5];
  const float* output_b = (const float*)d_in[6];
  float* out = (float*)d_out;

  char* ws = (char*)d_ws;
  size_t off = 0;
  auto alloc = [&](size_t bytes) -> void* {
    void* p = ws + off;
    off += (bytes + 255) & ~(size_t)255;
    return p;
  };
  f16* hidden_h = (f16*)alloc((size_t)T_TOK * H_DIM * 2);          // [8192][1024]
  f16* lw_t     = (f16*)alloc((size_t)NHEAD * H_DIM * H_DIM * 2);  // [8192][1024]
  f16* ow_t     = (f16*)alloc((size_t)V_DIM * H_DIM * 2);          // [2048][1024]
  float* prior  = (float*)alloc((size_t)T_TOK * NHEAD * 4);

  // tc=8192 (R6: per-work GEMM 2x faster at large grids; R4: ws fits)
  int tc = T_TOK;
  while (tc > 256) {
    size_t need = off + (size_t)tc * NHEAD * H_DIM * 2 + 256 +
                  (size_t)tc * NHEAD * V_DIM * 2 + 256;
    if (need <= ws_size) break;
    tc >>= 1;
  }
  f16* latent_h = (f16*)alloc((size_t)tc * NHEAD * H_DIM * 2);  // [tc*8][1024]
  f16* logits_h = (f16*)alloc((size_t)tc * NHEAD * V_DIM * 2);  // [tc*8][2048]

  // prep passes
  k_convert<<<(T_TOK * H_DIM / 4 + 255) / 256, 256, 0, stream>>>(
      hidden, hidden_h, T_TOK * H_DIM / 4);
  k_transpose<<<dim3(NHEAD * H_DIM / 64, H_DIM / 64), 256, 0, stream>>>(
      latent_w, lw_t, H_DIM, NHEAD * H_DIM);
  k_transpose<<<dim3(V_DIM / 64, H_DIM / 64), 256, 0, stream>>>(
      output_w, ow_t, H_DIM, V_DIM);
  k_prior<<<T_TOK / 4, 256, 0, stream>>>(hidden, prior_w, prior_b, prior);

  const int nchunk = T_TOK / tc;
  for (int c = 0; c < nchunk; ++c) {
    const f16* Ah = hidden_h + (size_t)c * tc * H_DIM;
    // GEMM1: latent = tanh(hidden @ latent_w + b), n-major XCD swizzle
    k_gemm<1, 1><<<dim3(NHEAD * H_DIM / 256, tc / 256), 512, 0, stream>>>(
        Ah, lw_t, latent_b, latent_h, tc, NHEAD * H_DIM, H_DIM);
    // GEMM2: logits = latent @ output_w + b, m-major (R4-proven 1.83 PF)
    k_gemm<0, 0><<<dim3(V_DIM / 256, tc * NHEAD / 256), 512, 0, stream>>>(
        latent_h, ow_t, output_b, logits_h, tc * NHEAD, V_DIM, H_DIM);
    // softmax (no max pass) + prior-weighted combine
    k_softmax<<<tc, 256, 0, stream>>>(logits_h, prior + (size_t)c * tc * NHEAD,
                                      out + (size_t)c * tc * V_DIM);
  }
}